// Round 4
// baseline (1760.182 us; speedup 1.0000x reference)
//
#include <hip/hip_runtime.h>
#include <hip/hip_bf16.h>
#include <string.h>

typedef __hip_bfloat16 bf16;
typedef short v8s __attribute__((ext_vector_type(8)));
typedef float v4f __attribute__((ext_vector_type(4)));

#define H_ 128
#define P_ 6
#define K_ 4
#define NBR_CAP 48

__device__ __forceinline__ float ldf(const float* p, size_t i) { return p[i]; }
__device__ __forceinline__ float ldf(const bf16* p, size_t i) { return __bfloat162float(p[i]); }

__device__ __forceinline__ float s2f(short s) {
    unsigned int u = ((unsigned int)(unsigned short)s) << 16;
    float f; __builtin_memcpy(&f, &u, 4); return f;
}
__device__ __forceinline__ short f2s(float v) {
    bf16 h = __float2bfloat16(v);
    short s; __builtin_memcpy(&s, &h, 2); return s;
}
__device__ __forceinline__ unsigned pack2(float a0, float a1) {
    return ((unsigned)(unsigned short)f2s(a1) << 16) | (unsigned)(unsigned short)f2s(a0);
}
__device__ __forceinline__ v4f MFMA(v8s a, v8s b, v4f c) {
    return __builtin_amdgcn_mfma_f32_16x16x32_bf16(a, b, c, 0, 0, 0);
}

// ---------------- CSR build: neighbor u8 lists + degree + float rowsum ----------------
__global__ __launch_bounds__(128) void k_csr(const float* __restrict__ adj,
    unsigned char* __restrict__ nbr, int* __restrict__ deg, float* __restrict__ degf)
{
    const int gi = blockIdx.x * 128 + threadIdx.x;   // (g,i), 4096 rows
    const float* row = adj + (size_t)gi * 128;
    unsigned char* nb = nbr + (size_t)gi * NBR_CAP;
    int c = 0; float s = 0.f;
    for (int j = 0; j < 128; ++j) {
        float a = row[j];
        if (a != 0.f) { s += a; if (c < NBR_CAP) nb[c] = (unsigned char)j; ++c; }
    }
    deg[gi] = (c < NBR_CAP) ? c : NBR_CAP;
    degf[gi] = s;
}

// ---------------- transpose 15 (128x128) weights to bf16 WT[w][n][k] ----------------
// 0: in_W2 | 1+2l/2+2l: gW1/gW2 l=0..2 | 7+2l/8+2l: iW1/iW2 l=0..1 | 11+2l/12+2l: glW1/glW2
__global__ __launch_bounds__(128) void k_wt(
    const float* in_W2, const float* gW1, const float* gW2,
    const float* iW1, const float* iW2, const float* glW1, const float* glW2,
    bf16* __restrict__ dst)
{
    const int w = blockIdx.x >> 7, n = blockIdx.x & 127, k = threadIdx.x;
    const float* s;
    switch (w) {
        case 0:  s = in_W2; break;
        case 1:  s = gW1; break;           case 2:  s = gW2; break;
        case 3:  s = gW1 + 16384; break;   case 4:  s = gW2 + 16384; break;
        case 5:  s = gW1 + 32768; break;   case 6:  s = gW2 + 32768; break;
        case 7:  s = iW1; break;           case 8:  s = iW2; break;
        case 9:  s = iW1 + 16384; break;   case 10: s = iW2 + 16384; break;
        case 11: s = glW1; break;          case 12: s = glW2; break;
        case 13: s = glW1 + 16384; break;  default: s = glW2 + 16384; break;
    }
    dst[(size_t)w * 16384 + n * 128 + k] = __float2bfloat16(s[k * 128 + n]);
}

// ---------------- generic VALU fused block (small tails only) ----------------
template<bool DO_MM1, bool HAS_RES>
__global__ __launch_bounds__(128) void k_block(
    const float* __restrict__ in, const float* __restrict__ res, float* __restrict__ out,
    const float* __restrict__ W1, const float* __restrict__ b1,
    const float* __restrict__ W2, const float* __restrict__ b2,
    const float* __restrict__ gam, const float* __restrict__ bet)
{
    __shared__ float sA[16][136];
    __shared__ float sB[16][136];
    __shared__ float sStat[32];
    const int hd = threadIdx.x;
    const size_t row0 = (size_t)blockIdx.x * 16;
    #pragma unroll
    for (int r = 0; r < 16; ++r) sA[r][hd] = in[(row0 + r) * H_ + hd];
    __syncthreads();
    float acc[16];
    if (DO_MM1) {
        #pragma unroll
        for (int r = 0; r < 16; ++r) acc[r] = b1[hd];
        for (int k = 0; k < H_; k += 4) {
            float w0 = W1[(k+0)*H_+hd], w1 = W1[(k+1)*H_+hd], w2 = W1[(k+2)*H_+hd], w3 = W1[(k+3)*H_+hd];
            #pragma unroll
            for (int r = 0; r < 16; ++r) {
                float4 a = *(const float4*)&sA[r][k];
                acc[r] = fmaf(a.x, w0, acc[r]); acc[r] = fmaf(a.y, w1, acc[r]);
                acc[r] = fmaf(a.z, w2, acc[r]); acc[r] = fmaf(a.w, w3, acc[r]);
            }
        }
        #pragma unroll
        for (int r = 0; r < 16; ++r) sB[r][hd] = fmaxf(acc[r], 0.f);
    } else {
        #pragma unroll
        for (int r = 0; r < 16; ++r) sB[r][hd] = sA[r][hd];
    }
    __syncthreads();
    #pragma unroll
    for (int r = 0; r < 16; ++r) acc[r] = b2[hd];
    for (int k = 0; k < H_; k += 4) {
        float w0 = W2[(k+0)*H_+hd], w1 = W2[(k+1)*H_+hd], w2 = W2[(k+2)*H_+hd], w3 = W2[(k+3)*H_+hd];
        #pragma unroll
        for (int r = 0; r < 16; ++r) {
            float4 a = *(const float4*)&sB[r][k];
            acc[r] = fmaf(a.x, w0, acc[r]); acc[r] = fmaf(a.y, w1, acc[r]);
            acc[r] = fmaf(a.z, w2, acc[r]); acc[r] = fmaf(a.w, w3, acc[r]);
        }
    }
    __syncthreads();
    #pragma unroll
    for (int r = 0; r < 16; ++r) sA[r][hd] = acc[r];
    __syncthreads();
    if (hd < 16) {
        float s = 0.f, ss = 0.f;
        for (int k = 0; k < H_; ++k) { float v = sA[hd][k]; s += v; ss += v * v; }
        float mean = s * (1.f / H_);
        float var = ss * (1.f / H_) - mean * mean;
        sStat[hd] = mean; sStat[16 + hd] = rsqrtf(var + 1e-5f);
    }
    __syncthreads();
    float gv = gam[hd], bv = bet[hd];
    #pragma unroll
    for (int r = 0; r < 16; ++r) {
        float v = fmaxf((acc[r] - sStat[r]) * sStat[16 + r] * gv + bv, 0.f);
        if (HAS_RES) v += res[(row0 + r) * H_ + hd];
        out[(row0 + r) * H_ + hd] = v;
    }
}

// ---------------- gemm + bias + relu (+ optional gathered residual from h) ----------------
template<bool GATHER, typename T>
__global__ __launch_bounds__(128) void k_gemm_relu(
    const T* __restrict__ in, const float* __restrict__ res, float* __restrict__ out,
    const float* __restrict__ W, const float* __restrict__ b)
{
    __shared__ float sA[16][136];
    const int hd = threadIdx.x;
    const size_t row0 = (size_t)blockIdx.x * 16;
    #pragma unroll
    for (int r = 0; r < 16; ++r) sA[r][hd] = ldf(in, (row0 + r) * H_ + hd);
    __syncthreads();
    float acc[16];
    #pragma unroll
    for (int r = 0; r < 16; ++r) acc[r] = b[hd];
    for (int k = 0; k < H_; k += 4) {
        float w0 = W[(k+0)*H_+hd], w1 = W[(k+1)*H_+hd], w2 = W[(k+2)*H_+hd], w3 = W[(k+3)*H_+hd];
        #pragma unroll
        for (int r = 0; r < 16; ++r) {
            float4 a = *(const float4*)&sA[r][k];
            acc[r] = fmaf(a.x, w0, acc[r]); acc[r] = fmaf(a.y, w1, acc[r]);
            acc[r] = fmaf(a.z, w2, acc[r]); acc[r] = fmaf(a.w, w3, acc[r]);
        }
    }
    #pragma unroll
    for (int r = 0; r < 16; ++r) {
        size_t rr = row0 + r;
        float v = fmaxf(acc[r], 0.f);
        if (GATHER) {
            int i = (int)(rr & 127);
            int g = (int)(rr >> 11);          // rr/(128*16)
            v += res[((size_t)(g * 128 + i)) * H_ + hd];
        }
        out[rr * H_ + hd] = v;
    }
}

// ---------------- g3: input embedding + 3 graph MP layers, one block per graph ----------------
__global__ __launch_bounds__(256) void k_g3(
    const float* __restrict__ x, const float* __restrict__ in_W1,
    const float* __restrict__ in_b1, const float* __restrict__ in_b2,
    const float* __restrict__ in_g, const float* __restrict__ in_bn,
    const float* __restrict__ gb1, const float* __restrict__ gb2,
    const float* __restrict__ gg, const float* __restrict__ gbn,
    const bf16* __restrict__ WT,
    const unsigned char* __restrict__ nbr, const int* __restrict__ deg,
    float* __restrict__ hb)
{
    __shared__ float hM[128][132];
    __shared__ __align__(16) short smem[4][32][136];
    const int t = threadIdx.x, lane = t & 63, wave = t >> 6;
    const int quad = lane >> 4, l16 = lane & 15;
    const int g = blockIdx.x;
    v4f acc[2][8];
    // ---- embedding: t1 = relu(x*W1+b1) into smem (bf16) ----
    {
        const int c = lane * 2;
        float w0 = in_W1[c], w1 = in_W1[c + 1];
        float bb0 = in_b1[c], bb1 = in_b1[c + 1];
        for (int r = 0; r < 32; ++r) {
            float xv = x[g * 128 + wave * 32 + r];
            *(unsigned*)&smem[wave][r][c] =
                pack2(fmaxf(fmaf(xv, w0, bb0), 0.f), fmaxf(fmaf(xv, w1, bb1), 0.f));
        }
    }
    // ---- embedding MM2 + LN + relu -> hM ----
    {
        const bf16* W2t = WT;   // in_W2t
        #pragma unroll
        for (int mt = 0; mt < 2; ++mt)
            #pragma unroll
            for (int nt = 0; nt < 8; ++nt) acc[mt][nt] = (v4f){0.f,0.f,0.f,0.f};
        #pragma unroll
        for (int kk = 0; kk < 4; ++kk) {
            v8s a0 = *(const v8s*)&smem[wave][l16][kk*32 + quad*8];
            v8s a1 = *(const v8s*)&smem[wave][16 + l16][kk*32 + quad*8];
            #pragma unroll
            for (int nt = 0; nt < 8; ++nt) {
                v8s b = *(const v8s*)(W2t + (nt*16 + l16)*128 + kk*32 + quad*8);
                acc[0][nt] = MFMA(a0, b, acc[0][nt]);
                acc[1][nt] = MFMA(a1, b, acc[1][nt]);
            }
        }
        float bb2[8], gv[8], bv[8];
        #pragma unroll
        for (int nt = 0; nt < 8; ++nt) {
            int n = nt*16 + l16;
            bb2[nt] = in_b2[n]; gv[nt] = in_g[n]; bv[nt] = in_bn[n];
        }
        #pragma unroll
        for (int mt = 0; mt < 2; ++mt)
            #pragma unroll
            for (int r = 0; r < 4; ++r) {
                float s = 0.f, q = 0.f;
                #pragma unroll
                for (int nt = 0; nt < 8; ++nt) {
                    float u = acc[mt][nt][r] + bb2[nt];
                    acc[mt][nt][r] = u; s += u; q += u*u;
                }
                #pragma unroll
                for (int d = 1; d < 16; d <<= 1) { s += __shfl_xor(s, d); q += __shfl_xor(q, d); }
                float mn = s * (1.f/128.f);
                float rs = rsqrtf(q * (1.f/128.f) - mn*mn + 1e-5f);
                int row = wave*32 + mt*16 + quad*4 + r;
                #pragma unroll
                for (int nt = 0; nt < 8; ++nt)
                    hM[row][nt*16 + l16] = fmaxf((acc[mt][nt][r] - mn)*rs*gv[nt] + bv[nt], 0.f);
            }
    }
    __syncthreads();
    // ---- 3 graph layers ----
    for (int l = 0; l < 3; ++l) {
        // gather m = sum_{j in N(i)} h[j] from LDS
        {
            const int c = lane * 2;
            for (int r = 0; r < 32; ++r) {
                int gi = g * 128 + wave * 32 + r;
                int cnt = deg[gi];
                const unsigned char* nb = nbr + (size_t)gi * NBR_CAP;
                float a0 = 0.f, a1 = 0.f;
                for (int cc = 0; cc < cnt; ++cc) {
                    int j = nb[cc];
                    a0 += hM[j][c]; a1 += hM[j][c + 1];
                }
                *(unsigned*)&smem[wave][r][c] = pack2(a0, a1);
            }
        }
        __syncthreads();   // all hM reads done before epilogue writes
        const bf16* W1t = WT + (size_t)(1 + 2*l) * 16384;
        const bf16* W2t = WT + (size_t)(2 + 2*l) * 16384;
        #pragma unroll
        for (int mt = 0; mt < 2; ++mt)
            #pragma unroll
            for (int nt = 0; nt < 8; ++nt) acc[mt][nt] = (v4f){0.f,0.f,0.f,0.f};
        #pragma unroll
        for (int kk = 0; kk < 4; ++kk) {
            v8s a0 = *(const v8s*)&smem[wave][l16][kk*32 + quad*8];
            v8s a1 = *(const v8s*)&smem[wave][16 + l16][kk*32 + quad*8];
            #pragma unroll
            for (int nt = 0; nt < 8; ++nt) {
                v8s b = *(const v8s*)(W1t + (nt*16 + l16)*128 + kk*32 + quad*8);
                acc[0][nt] = MFMA(a0, b, acc[0][nt]);
                acc[1][nt] = MFMA(a1, b, acc[1][nt]);
            }
        }
        #pragma unroll
        for (int nt = 0; nt < 8; ++nt) {
            float bb = gb1[l*128 + nt*16 + l16];
            #pragma unroll
            for (int mt = 0; mt < 2; ++mt)
                #pragma unroll
                for (int r = 0; r < 4; ++r)
                    smem[wave][mt*16 + quad*4 + r][nt*16 + l16] = f2s(fmaxf(acc[mt][nt][r] + bb, 0.f));
        }
        #pragma unroll
        for (int mt = 0; mt < 2; ++mt)
            #pragma unroll
            for (int nt = 0; nt < 8; ++nt) acc[mt][nt] = (v4f){0.f,0.f,0.f,0.f};
        #pragma unroll
        for (int kk = 0; kk < 4; ++kk) {
            v8s a0 = *(const v8s*)&smem[wave][l16][kk*32 + quad*8];
            v8s a1 = *(const v8s*)&smem[wave][16 + l16][kk*32 + quad*8];
            #pragma unroll
            for (int nt = 0; nt < 8; ++nt) {
                v8s b = *(const v8s*)(W2t + (nt*16 + l16)*128 + kk*32 + quad*8);
                acc[0][nt] = MFMA(a0, b, acc[0][nt]);
                acc[1][nt] = MFMA(a1, b, acc[1][nt]);
            }
        }
        float bb2[8], gv[8], bv[8];
        #pragma unroll
        for (int nt = 0; nt < 8; ++nt) {
            int n = nt*16 + l16;
            bb2[nt] = gb2[l*128 + n]; gv[nt] = gg[l*128 + n]; bv[nt] = gbn[l*128 + n];
        }
        #pragma unroll
        for (int mt = 0; mt < 2; ++mt)
            #pragma unroll
            for (int r = 0; r < 4; ++r) {
                float s = 0.f, q = 0.f;
                #pragma unroll
                for (int nt = 0; nt < 8; ++nt) {
                    float u = acc[mt][nt][r] + bb2[nt];
                    acc[mt][nt][r] = u; s += u; q += u*u;
                }
                #pragma unroll
                for (int d = 1; d < 16; d <<= 1) { s += __shfl_xor(s, d); q += __shfl_xor(q, d); }
                float mn = s * (1.f/128.f);
                float rs = rsqrtf(q * (1.f/128.f) - mn*mn + 1e-5f);
                int row = wave*32 + mt*16 + quad*4 + r;
                #pragma unroll
                for (int nt = 0; nt < 8; ++nt) {
                    float v = fmaxf((acc[mt][nt][r] - mn)*rs*gv[nt] + bv[nt], 0.f);
                    hM[row][nt*16 + l16] += v;
                }
            }
        __syncthreads();   // h updated before next layer's gather
    }
    // ---- write h out (coalesced) ----
    for (int u = 0; u < 64; ++u) {
        int idx = u * 256 + t;
        int row = idx >> 7, col = idx & 127;
        hb[((size_t)g * 128 + row) * 128 + col] = hM[row][col];
    }
}

// ---------------- ID layer 1, fully fused, 16 nodes (96 rows) per block ----------------
__global__ __launch_bounds__(256) void k_id1_fused(
    const float* __restrict__ adj, const float* __restrict__ degf,
    const int* __restrict__ subgs, const int* __restrict__ allperm,
    const float* __restrict__ idemb, bf16* __restrict__ z2,
    const bf16* __restrict__ W1t, const float* __restrict__ b1,
    const bf16* __restrict__ W2t, const float* __restrict__ b2,
    const float* __restrict__ gam, const float* __restrict__ bet)
{
    __shared__ __align__(16) short smem[4][32][136];
    __shared__ float sEm[4][128];
    __shared__ float sAq[16][4];
    __shared__ float sDg[16];
    __shared__ int   sPerm[24];
    __shared__ int   sSub[4];
    __shared__ int   sPos[16];
    const int t = threadIdx.x;
    const int b_s = blockIdx.x >> 3;
    const int node0 = (blockIdx.x & 7) * 16;
    const int g = b_s >> 4;
    if (t < 24) sPerm[t] = allperm[t];
    if (t < 4) sSub[t] = subgs[b_s * 4 + t];
    {
        int j = t >> 7, c = t & 127;
        sEm[j][c] = idemb[j * 128 + c] - 1.f;
        sEm[j + 2][c] = idemb[(j + 2) * 128 + c] - 1.f;
    }
    __syncthreads();
    if (t < 16) {
        sDg[t] = degf[g * 128 + node0 + t];
        int pos = -1;
        #pragma unroll
        for (int q = 0; q < 4; ++q) if (sSub[q] == node0 + t) pos = q;
        sPos[t] = pos;
    }
    if (t < 64) {
        int il = t >> 2, q = t & 3;
        sAq[il][q] = adj[((size_t)(g * 128 + node0 + il)) * 128 + sSub[q]];
    }
    __syncthreads();
    // stage 1: m rows (closed form), column-parallel
    {
        const int c = t & 127, rhalf = t >> 7;
        #pragma unroll
        for (int il8 = 0; il8 < 8; ++il8) {
            int il = rhalf * 8 + il8;
            float dg = sDg[il];
            float a0 = sAq[il][0], a1 = sAq[il][1], a2 = sAq[il][2], a3 = sAq[il][3];
            #pragma unroll
            for (int p = 0; p < 6; ++p) {
                float v = dg;
                v = fmaf(a0, sEm[sPerm[0*6 + p]][c], v);
                v = fmaf(a1, sEm[sPerm[1*6 + p]][c], v);
                v = fmaf(a2, sEm[sPerm[2*6 + p]][c], v);
                v = fmaf(a3, sEm[sPerm[3*6 + p]][c], v);
                int lr = il * 6 + p;
                smem[lr / 24][lr % 24][c] = f2s(v);
            }
        }
    }
    __syncthreads();
    // stage 2: MFMA MLP (24 valid rows per wave, padded to 32)
    const int lane = t & 63, wave = t >> 6;
    const int quad = lane >> 4, l16 = lane & 15;
    v4f acc[2][8];
    #pragma unroll
    for (int mt = 0; mt < 2; ++mt)
        #pragma unroll
        for (int nt = 0; nt < 8; ++nt) acc[mt][nt] = (v4f){0.f,0.f,0.f,0.f};
    #pragma unroll
    for (int kk = 0; kk < 4; ++kk) {
        v8s a0 = *(const v8s*)&smem[wave][l16][kk*32 + quad*8];
        v8s a1 = *(const v8s*)&smem[wave][16 + l16][kk*32 + quad*8];
        #pragma unroll
        for (int nt = 0; nt < 8; ++nt) {
            v8s b = *(const v8s*)(W1t + (nt*16 + l16)*128 + kk*32 + quad*8);
            acc[0][nt] = MFMA(a0, b, acc[0][nt]);
            acc[1][nt] = MFMA(a1, b, acc[1][nt]);
        }
    }
    #pragma unroll
    for (int nt = 0; nt < 8; ++nt) {
        float bb = b1[nt*16 + l16];
        #pragma unroll
        for (int mt = 0; mt < 2; ++mt)
            #pragma unroll
            for (int r = 0; r < 4; ++r)
                smem[wave][mt*16 + quad*4 + r][nt*16 + l16] = f2s(fmaxf(acc[mt][nt][r] + bb, 0.f));
    }
    #pragma unroll
    for (int mt = 0; mt < 2; ++mt)
        #pragma unroll
        for (int nt = 0; nt < 8; ++nt) acc[mt][nt] = (v4f){0.f,0.f,0.f,0.f};
    #pragma unroll
    for (int kk = 0; kk < 4; ++kk) {
        v8s a0 = *(const v8s*)&smem[wave][l16][kk*32 + quad*8];
        v8s a1 = *(const v8s*)&smem[wave][16 + l16][kk*32 + quad*8];
        #pragma unroll
        for (int nt = 0; nt < 8; ++nt) {
            v8s b = *(const v8s*)(W2t + (nt*16 + l16)*128 + kk*32 + quad*8);
            acc[0][nt] = MFMA(a0, b, acc[0][nt]);
            acc[1][nt] = MFMA(a1, b, acc[1][nt]);
        }
    }
    float bb2[8], gv[8], bv[8];
    #pragma unroll
    for (int nt = 0; nt < 8; ++nt) {
        int n = nt*16 + l16;
        bb2[nt] = b2[n]; gv[nt] = gam[n]; bv[nt] = bet[n];
    }
    #pragma unroll
    for (int mt = 0; mt < 2; ++mt)
        #pragma unroll
        for (int r = 0; r < 4; ++r) {
            float s = 0.f, q = 0.f;
            #pragma unroll
            for (int nt = 0; nt < 8; ++nt) {
                float u = acc[mt][nt][r] + bb2[nt];
                acc[mt][nt][r] = u; s += u; q += u*u;
            }
            #pragma unroll
            for (int d = 1; d < 16; d <<= 1) { s += __shfl_xor(s, d); q += __shfl_xor(q, d); }
            float mn = s * (1.f/128.f);
            float rs = rsqrtf(q * (1.f/128.f) - mn*mn + 1e-5f);
            int lrl = mt*16 + quad*4 + r;
            if (lrl < 24) {
                int lr = wave * 24 + lrl;
                int il = lr / 6, p = lr - il * 6;
                int pos = sPos[il];
                #pragma unroll
                for (int nt = 0; nt < 8; ++nt) {
                    int col = nt*16 + l16;
                    float self = (pos < 0) ? 1.f : (sEm[sPerm[pos*6 + p]][col] + 1.f);
                    float v = fmaxf((acc[mt][nt][r] - mn)*rs*gv[nt] + bv[nt], 0.f) + self;
                    smem[wave][lrl][col] = f2s(v);
                }
            }
        }
    __syncthreads();
    // stage 3: coalesced z2 store
    const size_t base = ((size_t)(b_s * 128 + node0)) * 6;
    #pragma unroll
    for (int k2 = 0; k2 < 6; ++k2) {
        int chunk = t + k2 * 256;               // 0..1535
        int row = chunk >> 4, c8 = chunk & 15;
        v8s v = *(const v8s*)&smem[row / 24][row % 24][c8 * 8];
        *(v8s*)(z2 + (base + row) * 128 + c8 * 8) = v;
    }
}

// ---------------- ID layer 2, fully fused, 16 nodes (96 rows) per block ----------------
__global__ __launch_bounds__(256) void k_id2_fused(
    const bf16* __restrict__ z2, bf16* __restrict__ zm,
    const unsigned char* __restrict__ nbr, const int* __restrict__ deg,
    const int* __restrict__ num_node,
    const bf16* __restrict__ W1t, const float* __restrict__ b1,
    const bf16* __restrict__ W2t, const float* __restrict__ b2,
    const float* __restrict__ gam, const float* __restrict__ bet)
{
    __shared__ __align__(16) short smem[4][32][136];
    const int t = threadIdx.x, lane = t & 63, wave = t >> 6;
    const int quad = lane >> 4, l16 = lane & 15;
    const int b_s = blockIdx.x >> 3;
    const int node0 = (blockIdx.x & 7) * 16;
    const int g = b_s >> 4;
    const size_t base = ((size_t)(b_s * 128 + node0)) * 6;
    // stage 1: wave-coalesced gather of m rows (lane = 2 cols)
    {
        const unsigned* zrow = (const unsigned*)(z2 + ((size_t)b_s * 128) * 768) + lane;
        for (int r = 0; r < 24; ++r) {
            int lr = wave * 24 + r;
            int il = lr / 6, p = lr - il * 6;
            int gi = g * 128 + node0 + il;
            int cnt = deg[gi];
            const unsigned char* nb = nbr + (size_t)gi * NBR_CAP;
            float a0 = 0.f, a1 = 0.f;
            const unsigned* zp = zrow + p * 64;
            for (int c = 0; c < cnt; ++c) {
                unsigned u = zp[(int)nb[c] * 384];
                a0 += s2f((short)(u & 0xffff));
                a1 += s2f((short)(u >> 16));
            }
            *(unsigned*)&smem[wave][r][lane * 2] = pack2(a0, a1);
        }
    }
    // stage 2: MFMA MLP (wave-private; no block syncs needed)
    v4f acc[2][8];
    #pragma unroll
    for (int mt = 0; mt < 2; ++mt)
        #pragma unroll
        for (int nt = 0; nt < 8; ++nt) acc[mt][nt] = (v4f){0.f,0.f,0.f,0.f};
    #pragma unroll
    for (int kk = 0; kk < 4; ++kk) {
        v8s a0 = *(const v8s*)&smem[wave][l16][kk*32 + quad*8];
        v8s a1 = *(const v8s*)&smem[wave][16 + l16][kk*32 + quad*8];
        #pragma unroll
        for (int nt = 0; nt < 8; ++nt) {
            v8s b = *(const v8s*)(W1t + (nt*16 + l16)*128 + kk*32 + quad*8);
            acc[0][nt] = MFMA(a0, b, acc[0][nt]);
            acc[1][nt] = MFMA(a1, b, acc[1][nt]);
        }
    }
    #pragma unroll
    for (int nt = 0; nt < 8; ++nt) {
        float bb = b1[nt*16 + l16];
        #pragma unroll
        for (int mt = 0; mt < 2; ++mt)
            #pragma unroll
            for (int r = 0; r < 4; ++r)
                smem[wave][mt*16 + quad*4 + r][nt*16 + l16] = f2s(fmaxf(acc[mt][nt][r] + bb, 0.f));
    }
    #pragma unroll
    for (int mt = 0; mt < 2; ++mt)
        #pragma unroll
        for (int nt = 0; nt < 8; ++nt) acc[mt][nt] = (v4f){0.f,0.f,0.f,0.f};
    #pragma unroll
    for (int kk = 0; kk < 4; ++kk) {
        v8s a0 = *(const v8s*)&smem[wave][l16][kk*32 + quad*8];
        v8s a1 = *(const v8s*)&smem[wave][16 + l16][kk*32 + quad*8];
        #pragma unroll
        for (int nt = 0; nt < 8; ++nt) {
            v8s b = *(const v8s*)(W2t + (nt*16 + l16)*128 + kk*32 + quad*8);
            acc[0][nt] = MFMA(a0, b, acc[0][nt]);
            acc[1][nt] = MFMA(a1, b, acc[1][nt]);
        }
    }
    // stage 3: bias, LN, relu, + z2 residual -> back to LDS (bf16)
    float bb2[8], gv[8], bv[8];
    #pragma unroll
    for (int nt = 0; nt < 8; ++nt) {
        int n = nt*16 + l16;
        bb2[nt] = b2[n]; gv[nt] = gam[n]; bv[nt] = bet[n];
    }
    #pragma unroll
    for (int mt = 0; mt < 2; ++mt)
        #pragma unroll
        for (int r = 0; r < 4; ++r) {
            float s = 0.f, q = 0.f;
            #pragma unroll
            for (int nt = 0; nt < 8; ++nt) {
                float u = acc[mt][nt][r] + bb2[nt];
                acc[mt][nt][r] = u; s += u; q += u*u;
            }
            #pragma unroll
            for (int d = 1; d < 16; d <<= 1) { s += __shfl_xor(s, d); q += __shfl_xor(q, d); }
            float mn = s * (1.f/128.f);
            float rs = rsqrtf(q * (1.f/128.f) - mn*mn + 1e-5f);
            int lrl = mt*16 + quad*4 + r;
            if (lrl < 24) {
                #pragma unroll
                for (int nt = 0; nt < 8; ++nt) {
                    int col = nt*16 + l16;
                    float v = fmaxf((acc[mt][nt][r] - mn)*rs*gv[nt] + bv[nt], 0.f);
                    v += __bfloat162float(z2[(base + wave*24 + lrl) * 128 + col]);
                    smem[wave][lrl][col] = f2s(v);
                }
            }
        }
    // stage 4: p-mean per node (wave-private rows), masked, coalesced zm store
    const int n_l = lane >> 4;            // node within wave (4)
    const int c0 = (lane & 15) * 8;       // 8 cols per lane
    const int i_g = node0 + wave * 4 + n_l;
    float sum[8] = {0.f,0.f,0.f,0.f,0.f,0.f,0.f,0.f};
    #pragma unroll
    for (int p = 0; p < 6; ++p) {
        v8s v = *(const v8s*)&smem[wave][n_l * 6 + p][c0];
        #pragma unroll
        for (int u = 0; u < 8; ++u) sum[u] += s2f(v[u]);
    }
    const bool nul = (i_g >= num_node[g]);
    v8s ov;
    #pragma unroll
    for (int u = 0; u < 8; ++u) ov[u] = f2s(nul ? 0.f : sum[u] * (1.f/6.f));
    *(v8s*)(zm + ((size_t)(b_s * 128 + i_g)) * 128 + c0) = ov;
}

// ---------------- gl layer: gather + MFMA MLP + LN + residual (ping-pong) ----------------
__global__ __launch_bounds__(256) void k_gl_fused(
    const float* __restrict__ hsA, float* __restrict__ hsB,
    const unsigned char* __restrict__ nbr, const int* __restrict__ deg,
    const bf16* __restrict__ W1t, const float* __restrict__ b1,
    const bf16* __restrict__ W2t, const float* __restrict__ b2,
    const float* __restrict__ gam, const float* __restrict__ bet)
{
    __shared__ __align__(16) short smem[4][16][136];
    const int t = threadIdx.x, lane = t & 63, wave = t >> 6;
    const int quad = lane >> 4, l16 = lane & 15;
    const int b_s = blockIdx.x >> 1;
    const int node0 = (blockIdx.x & 1) * 64;
    const int g = b_s >> 4;
    const float* hblk = hsA + (size_t)b_s * 128 * 128;
    // gather (wave-coalesced, lane = 2 cols)
    {
        const float* hp = hblk + lane * 2;
        for (int r = 0; r < 16; ++r) {
            int gi = g * 128 + node0 + wave * 16 + r;
            int cnt = deg[gi];
            const unsigned char* nb = nbr + (size_t)gi * NBR_CAP;
            float a0 = 0.f, a1 = 0.f;
            for (int c = 0; c < cnt; ++c) {
                const float* qp = hp + (int)nb[c] * 128;
                a0 += qp[0]; a1 += qp[1];
            }
            *(unsigned*)&smem[wave][r][lane * 2] = pack2(a0, a1);
        }
    }
    v4f acc[8];
    #pragma unroll
    for (int nt = 0; nt < 8; ++nt) acc[nt] = (v4f){0.f,0.f,0.f,0.f};
    #pragma unroll
    for (int kk = 0; kk < 4; ++kk) {
        v8s a = *(const v8s*)&smem[wave][l16][kk*32 + quad*8];
        #pragma unroll
        for (int nt = 0; nt < 8; ++nt) {
            v8s b = *(const v8s*)(W1t + (nt*16 + l16)*128 + kk*32 + quad*8);
            acc[nt] = MFMA(a, b, acc[nt]);
        }
    }
    #pragma unroll
    for (int nt = 0; nt < 8; ++nt) {
        float bb = b1[nt*16 + l16];
        #pragma unroll
        for (int r = 0; r < 4; ++r)
            smem[wave][quad*4 + r][nt*16 + l16] = f2s(fmaxf(acc[nt][r] + bb, 0.f));
    }
    #pragma unroll
    for (int nt = 0; nt < 8; ++nt) acc[nt] = (v4f){0.f,0.f,0.f,0.f};
    #pragma unroll
    for (int kk = 0; kk < 4; ++kk) {
        v8s a = *(const v8s*)&smem[wave][l16][kk*32 + quad*8];
        #pragma unroll
        for (int nt = 0; nt < 8; ++nt) {
            v8s b = *(const v8s*)(W2t + (nt*16 + l16)*128 + kk*32 + quad*8);
            acc[nt] = MFMA(a, b, acc[nt]);
        }
    }
    float bb2[8], gv[8], bv[8];
    #pragma unroll
    for (int nt = 0; nt < 8; ++nt) {
        int n = nt*16 + l16;
        bb2[nt] = b2[n]; gv[nt] = gam[n]; bv[nt] = bet[n];
    }
    #pragma unroll
    for (int r = 0; r < 4; ++r) {
        float s = 0.f, q = 0.f;
        #pragma unroll
        for (int nt = 0; nt < 8; ++nt) {
            float u = acc[nt][r] + bb2[nt];
            acc[nt][r] = u; s += u; q += u*u;
        }
        #pragma unroll
        for (int d = 1; d < 16; d <<= 1) { s += __shfl_xor(s, d); q += __shfl_xor(q, d); }
        float mn = s * (1.f/128.f);
        float rs = rsqrtf(q * (1.f/128.f) - mn*mn + 1e-5f);
        size_t gr = ((size_t)b_s * 128 + node0 + wave*16 + quad*4 + r) * 128;
        #pragma unroll
        for (int nt = 0; nt < 8; ++nt) {
            int col = nt*16 + l16;
            float v = fmaxf((acc[nt][r] - mn)*rs*gv[nt] + bv[nt], 0.f);
            hsB[gr + col] = v + hsA[gr + col];
        }
    }
}

// ---------------- hs.sum(axis=1) ----------------
__global__ __launch_bounds__(128) void k_hssum(const float* __restrict__ hs, float* __restrict__ hsum)
{
    const int b_s = blockIdx.x, hd = threadIdx.x;
    float v = 0.f;
    const float* r = hs + (size_t)b_s * 128 * H_ + hd;
    for (int i = 0; i < 128; ++i) v += r[(size_t)i * H_];
    hsum[(size_t)b_s * H_ + hd] = v;
}

// ---------------- segment max over 16 subgraphs per graph ----------------
__global__ __launch_bounds__(128) void k_maxpool(const float* __restrict__ hs2, float* __restrict__ pooled)
{
    const int g = blockIdx.x, hd = threadIdx.x;
    float m = -INFINITY;
    for (int s = 0; s < 16; ++s) m = fmaxf(m, hs2[((size_t)(g * 16 + s)) * H_ + hd]);
    pooled[(size_t)g * H_ + hd] = m;
}

// ---------------- final projection ----------------
__global__ __launch_bounds__(128) void k_out(const float* __restrict__ pooled2,
    const float* __restrict__ out_W, const float* __restrict__ out_b, float* __restrict__ out)
{
    __shared__ float red[128];
    const int g = blockIdx.x, hd = threadIdx.x;
    red[hd] = pooled2[(size_t)g * H_ + hd] * out_W[hd];
    __syncthreads();
    for (int s = 64; s > 0; s >>= 1) {
        if (hd < s) red[hd] += red[hd + s];
        __syncthreads();
    }
    if (hd == 0) out[g] = red[0] + out_b[0];
}

extern "C" void kernel_launch(void* const* d_in, const int* in_sizes, int n_in,
                              void* d_out, int out_size, void* d_ws, size_t ws_size,
                              hipStream_t stream)
{
    (void)in_sizes; (void)n_in; (void)out_size; (void)ws_size;
    const float* x     = (const float*)d_in[0];
    const float* adj   = (const float*)d_in[1];
    const float* idemb = (const float*)d_in[2];
    const float* in_W1 = (const float*)d_in[3];
    const float* in_b1 = (const float*)d_in[4];
    const float* in_W2 = (const float*)d_in[5];
    const float* in_b2 = (const float*)d_in[6];
    const float* in_g  = (const float*)d_in[7];
    const float* in_bn = (const float*)d_in[8];
    const float* gW1   = (const float*)d_in[9];
    const float* gb1   = (const float*)d_in[10];
    const float* gW2   = (const float*)d_in[11];
    const float* gb2   = (const float*)d_in[12];
    const float* gg    = (const float*)d_in[13];
    const float* gbn   = (const float*)d_in[14];
    const float* iW1   = (const float*)d_in[15];
    const float* ib1   = (const float*)d_in[16];
    const float* iW2   = (const float*)d_in[17];
    const float* ib2   = (const float*)d_in[18];
    const float* ig    = (const float*)d_in[19];
    const float* ibn   = (const float*)d_in[20];
    const float* glW1  = (const float*)d_in[21];
    const float* glb1  = (const float*)d_in[22];
    const float* glW2  = (const float*)d_in[23];
    const float* glb2  = (const float*)d_in[24];
    const float* glg   = (const float*)d_in[25];
    const float* glbn  = (const float*)d_in[26];
    const float* s1_W  = (const float*)d_in[27];
    const float* s1_b  = (const float*)d_in[28];
    const float* s2_W  = (const float*)d_in[29];
    const float* s2_b  = (const float*)d_in[30];
    const float* rW1   = (const float*)d_in[31];
    const float* rb1   = (const float*)d_in[32];
    const float* rW2   = (const float*)d_in[33];
    const float* rb2   = (const float*)d_in[34];
    const float* rg    = (const float*)d_in[35];
    const float* rbn   = (const float*)d_in[36];
    const float* out_W = (const float*)d_in[37];
    const float* out_b = (const float*)d_in[38];
    const int* subgs   = (const int*)d_in[39];
    const int* num_node= (const int*)d_in[41];
    const int* allperm = (const int*)d_in[42];

    // ---- workspace layout (peak ~115 MB) ----
    const size_t MB_ = (size_t)512 * 128 * P_ * H_ * 2;        // 100,663,296: z2
    char* w = (char*)d_ws;
    bf16*  z2b    = (bf16*)(w);                                 // region A: z2
    float* hsA    = (float*)(w);                                // region A reuse (z2 dead)
    float* hsB    = (float*)(w + 33554432ull);                  // region A reuse
    bf16*  zm     = (bf16*)(w + MB_);                           // (512,128,128) bf16 = 16.8 MB
    bf16*  WT     = (bf16*)(w + MB_ + 16777216ull);             // 15 x (128x128) bf16 transposed
    char*  wc     = w + MB_ + 16777216ull + 524288ull;
    float* hb     = (float*)(wc);                               // h (32,128,128) f32  2 MB
    float* hsum   = (float*)(wc + 2097152ull);                  // (512,128)
    float* hs2    = (float*)(wc + 2359296ull);                  // (512,128)
    float* pooled = (float*)(wc + 2621440ull);                  // (32,128)
    float* pooled2= (float*)(wc + 2637824ull);                  // (32,128)
    unsigned char* nbr = (unsigned char*)(wc + 2654208ull);     // 4096*48 u8
    int*   deg    = (int*)(wc + 2850816ull);                    // 4096 i32
    float* degf   = (float*)(wc + 2867200ull);                  // 4096 f32
    float* outp   = (float*)d_out;

    // prep: CSR + transposed bf16 weights
    k_csr<<<32, 128, 0, stream>>>(adj, nbr, deg, degf);
    k_wt<<<1920, 128, 0, stream>>>(in_W2, gW1, gW2, iW1, iW2, glW1, glW2, WT);

    // input embedding + 3 graph MP layers (one kernel)
    k_g3<<<32, 256, 0, stream>>>(x, in_W1, in_b1, in_b2, in_g, in_bn,
        gb1, gb2, gg, gbn, WT, nbr, deg, hb);

    // ID layer 1 fully fused -> z2
    k_id1_fused<<<4096, 256, 0, stream>>>(adj, degf, subgs, allperm, idemb, z2b,
        WT + (size_t)7 * 16384, ib1, WT + (size_t)8 * 16384, ib2, ig, ibn);

    // ID layer 2 fully fused -> zm (z3 never materialized)
    k_id2_fused<<<4096, 256, 0, stream>>>(z2b, zm, nbr, deg, num_node,
        WT + (size_t)9 * 16384, ib1 + 128, WT + (size_t)10 * 16384, ib2 + 128, ig + 128, ibn + 128);

    // setmlp1 with gathered residual h[subgbatch] -> hsA (region A; z2 now dead)
    k_gemm_relu<true, bf16><<<4096, 128, 0, stream>>>(zm, hb, hsA, s1_W, s1_b);

    // global message passing on subgraph copies (2 layers), ping-pong hsA/hsB
    k_gl_fused<<<1024, 256, 0, stream>>>(hsA, hsB, nbr, deg,
        WT + (size_t)11 * 16384, glb1, WT + (size_t)12 * 16384, glb2, glg, glbn);
    k_gl_fused<<<1024, 256, 0, stream>>>(hsB, hsA, nbr, deg,
        WT + (size_t)13 * 16384, glb1 + 128, WT + (size_t)14 * 16384, glb2 + 128, glg + 128, glbn + 128);

    // node sum -> setmlp2 -> segment max -> setmlp3 block -> output proj
    k_hssum<<<512, 128, 0, stream>>>(hsA, hsum);
    k_gemm_relu<false, float><<<32, 128, 0, stream>>>(hsum, nullptr, hs2, s2_W, s2_b);
    k_maxpool<<<32, 128, 0, stream>>>(hs2, pooled);
    k_block<true, true><<<2, 128, 0, stream>>>(pooled, pooled, pooled2,
        rW1, rb1, rW2, rb2, rg, rbn);
    k_out<<<32, 128, 0, stream>>>(pooled2, out_W, out_b, outp);
}

// Round 5
// 1123.472 us; speedup vs baseline: 1.5667x; 1.5667x over previous
//
#include <hip/hip_runtime.h>
#include <hip/hip_bf16.h>
#include <string.h>

typedef __hip_bfloat16 bf16;
typedef short v8s __attribute__((ext_vector_type(8)));
typedef float v4f __attribute__((ext_vector_type(4)));

#define H_ 128
#define P_ 6
#define K_ 4
#define NBR_CAP 48

__device__ __forceinline__ float ldf(const float* p, size_t i) { return p[i]; }
__device__ __forceinline__ float ldf(const bf16* p, size_t i) { return __bfloat162float(p[i]); }

__device__ __forceinline__ float s2f(short s) {
    unsigned int u = ((unsigned int)(unsigned short)s) << 16;
    float f; __builtin_memcpy(&f, &u, 4); return f;
}
__device__ __forceinline__ short f2s(float v) {
    bf16 h = __float2bfloat16(v);
    short s; __builtin_memcpy(&s, &h, 2); return s;
}
__device__ __forceinline__ unsigned pack2(float a0, float a1) {
    return ((unsigned)(unsigned short)f2s(a1) << 16) | (unsigned)(unsigned short)f2s(a0);
}
__device__ __forceinline__ v4f MFMA(v8s a, v8s b, v4f c) {
    return __builtin_amdgcn_mfma_f32_16x16x32_bf16(a, b, c, 0, 0, 0);
}

// ---------------- CSR build: neighbor u8 lists + degree + float rowsum ----------------
__global__ __launch_bounds__(128) void k_csr(const float* __restrict__ adj,
    unsigned char* __restrict__ nbr, int* __restrict__ deg, float* __restrict__ degf)
{
    const int gi = blockIdx.x * 128 + threadIdx.x;   // (g,i), 4096 rows
    const float* row = adj + (size_t)gi * 128;
    unsigned char* nb = nbr + (size_t)gi * NBR_CAP;
    int c = 0; float s = 0.f;
    for (int j = 0; j < 128; ++j) {
        float a = row[j];
        if (a != 0.f) { s += a; if (c < NBR_CAP) nb[c] = (unsigned char)j; ++c; }
    }
    deg[gi] = (c < NBR_CAP) ? c : NBR_CAP;
    degf[gi] = s;
}

// ---------------- transpose 15 (128x128) weights to bf16 WT[w][n][k] ----------------
__global__ __launch_bounds__(128) void k_wt(
    const float* in_W2, const float* gW1, const float* gW2,
    const float* iW1, const float* iW2, const float* glW1, const float* glW2,
    bf16* __restrict__ dst)
{
    const int w = blockIdx.x >> 7, n = blockIdx.x & 127, k = threadIdx.x;
    const float* s;
    switch (w) {
        case 0:  s = in_W2; break;
        case 1:  s = gW1; break;           case 2:  s = gW2; break;
        case 3:  s = gW1 + 16384; break;   case 4:  s = gW2 + 16384; break;
        case 5:  s = gW1 + 32768; break;   case 6:  s = gW2 + 32768; break;
        case 7:  s = iW1; break;           case 8:  s = iW2; break;
        case 9:  s = iW1 + 16384; break;   case 10: s = iW2 + 16384; break;
        case 11: s = glW1; break;          case 12: s = glW2; break;
        case 13: s = glW1 + 16384; break;  default: s = glW2 + 16384; break;
    }
    dst[(size_t)w * 16384 + n * 128 + k] = __float2bfloat16(s[k * 128 + n]);
}

// ---------------- input embedding: t1 = relu(x * W1 + b1) ----------------
__global__ __launch_bounds__(128) void k_in_t1(const float* __restrict__ x,
    const float* __restrict__ W1, const float* __restrict__ b1, float* __restrict__ t1)
{
    int r = blockIdx.x, hd = threadIdx.x;
    t1[(size_t)r * H_ + hd] = fmaxf(fmaf(x[r], W1[hd], b1[hd]), 0.f);
}

// ---------------- generic VALU fused block ----------------
template<bool DO_MM1, bool HAS_RES>
__global__ __launch_bounds__(128) void k_block(
    const float* __restrict__ in, const float* __restrict__ res, float* __restrict__ out,
    const float* __restrict__ W1, const float* __restrict__ b1,
    const float* __restrict__ W2, const float* __restrict__ b2,
    const float* __restrict__ gam, const float* __restrict__ bet)
{
    __shared__ float sA[16][136];
    __shared__ float sB[16][136];
    __shared__ float sStat[32];
    const int hd = threadIdx.x;
    const size_t row0 = (size_t)blockIdx.x * 16;
    #pragma unroll
    for (int r = 0; r < 16; ++r) sA[r][hd] = in[(row0 + r) * H_ + hd];
    __syncthreads();
    float acc[16];
    if (DO_MM1) {
        #pragma unroll
        for (int r = 0; r < 16; ++r) acc[r] = b1[hd];
        for (int k = 0; k < H_; k += 4) {
            float w0 = W1[(k+0)*H_+hd], w1 = W1[(k+1)*H_+hd], w2 = W1[(k+2)*H_+hd], w3 = W1[(k+3)*H_+hd];
            #pragma unroll
            for (int r = 0; r < 16; ++r) {
                float4 a = *(const float4*)&sA[r][k];
                acc[r] = fmaf(a.x, w0, acc[r]); acc[r] = fmaf(a.y, w1, acc[r]);
                acc[r] = fmaf(a.z, w2, acc[r]); acc[r] = fmaf(a.w, w3, acc[r]);
            }
        }
        #pragma unroll
        for (int r = 0; r < 16; ++r) sB[r][hd] = fmaxf(acc[r], 0.f);
    } else {
        #pragma unroll
        for (int r = 0; r < 16; ++r) sB[r][hd] = sA[r][hd];
    }
    __syncthreads();
    #pragma unroll
    for (int r = 0; r < 16; ++r) acc[r] = b2[hd];
    for (int k = 0; k < H_; k += 4) {
        float w0 = W2[(k+0)*H_+hd], w1 = W2[(k+1)*H_+hd], w2 = W2[(k+2)*H_+hd], w3 = W2[(k+3)*H_+hd];
        #pragma unroll
        for (int r = 0; r < 16; ++r) {
            float4 a = *(const float4*)&sB[r][k];
            acc[r] = fmaf(a.x, w0, acc[r]); acc[r] = fmaf(a.y, w1, acc[r]);
            acc[r] = fmaf(a.z, w2, acc[r]); acc[r] = fmaf(a.w, w3, acc[r]);
        }
    }
    __syncthreads();
    #pragma unroll
    for (int r = 0; r < 16; ++r) sA[r][hd] = acc[r];
    __syncthreads();
    if (hd < 16) {
        float s = 0.f, ss = 0.f;
        for (int k = 0; k < H_; ++k) { float v = sA[hd][k]; s += v; ss += v * v; }
        float mean = s * (1.f / H_);
        float var = ss * (1.f / H_) - mean * mean;
        sStat[hd] = mean; sStat[16 + hd] = rsqrtf(var + 1e-5f);
    }
    __syncthreads();
    float gv = gam[hd], bv = bet[hd];
    #pragma unroll
    for (int r = 0; r < 16; ++r) {
        float v = fmaxf((acc[r] - sStat[r]) * sStat[16 + r] * gv + bv, 0.f);
        if (HAS_RES) v += res[(row0 + r) * H_ + hd];
        out[(row0 + r) * H_ + hd] = v;
    }
}

// ---------------- gemm + bias + relu (+ optional gathered residual from h) ----------------
template<bool GATHER, typename T>
__global__ __launch_bounds__(128) void k_gemm_relu(
    const T* __restrict__ in, const float* __restrict__ res, float* __restrict__ out,
    const float* __restrict__ W, const float* __restrict__ b)
{
    __shared__ float sA[16][136];
    const int hd = threadIdx.x;
    const size_t row0 = (size_t)blockIdx.x * 16;
    #pragma unroll
    for (int r = 0; r < 16; ++r) sA[r][hd] = ldf(in, (row0 + r) * H_ + hd);
    __syncthreads();
    float acc[16];
    #pragma unroll
    for (int r = 0; r < 16; ++r) acc[r] = b[hd];
    for (int k = 0; k < H_; k += 4) {
        float w0 = W[(k+0)*H_+hd], w1 = W[(k+1)*H_+hd], w2 = W[(k+2)*H_+hd], w3 = W[(k+3)*H_+hd];
        #pragma unroll
        for (int r = 0; r < 16; ++r) {
            float4 a = *(const float4*)&sA[r][k];
            acc[r] = fmaf(a.x, w0, acc[r]); acc[r] = fmaf(a.y, w1, acc[r]);
            acc[r] = fmaf(a.z, w2, acc[r]); acc[r] = fmaf(a.w, w3, acc[r]);
        }
    }
    #pragma unroll
    for (int r = 0; r < 16; ++r) {
        size_t rr = row0 + r;
        float v = fmaxf(acc[r], 0.f);
        if (GATHER) {
            int i = (int)(rr & 127);
            int g = (int)(rr >> 11);          // rr/(128*16)
            v += res[((size_t)(g * 128 + i)) * H_ + hd];
        }
        out[rr * H_ + hd] = v;
    }
}

// ---------------- dense sparse-matvec for g-layers ----------------
__global__ __launch_bounds__(128) void k_spmv(const float* __restrict__ adj,
    const float* __restrict__ xin, float* __restrict__ mout, int subShift)
{
    __shared__ float sAdj[128];
    const int hd = threadIdx.x;
    const int bi = blockIdx.x;
    const int bb = bi >> 7, i = bi & 127;
    const int g = bb >> subShift;
    sAdj[hd] = adj[((size_t)(g * 128 + i)) * 128 + hd];
    __syncthreads();
    float acc = 0.f;
    const float* xb = xin + (size_t)bb * 128 * H_ + hd;
    for (int j = 0; j < 128; ++j) {
        float a = sAdj[j];
        if (a != 0.f) acc = fmaf(a, xb[(size_t)j * H_], acc);
    }
    mout[(size_t)bi * H_ + hd] = acc;
}

// ---------------- ID layer 1, fully fused, 16 nodes (96 rows) per block ----------------
__global__ __launch_bounds__(256) void k_id1_fused(
    const float* __restrict__ adj, const float* __restrict__ degf,
    const int* __restrict__ subgs, const int* __restrict__ allperm,
    const float* __restrict__ idemb, bf16* __restrict__ z2,
    const bf16* __restrict__ W1t, const float* __restrict__ b1,
    const bf16* __restrict__ W2t, const float* __restrict__ b2,
    const float* __restrict__ gam, const float* __restrict__ bet)
{
    __shared__ __align__(16) short smem[4][32][136];
    __shared__ float sEm[4][128];
    __shared__ float sAq[16][4];
    __shared__ float sDg[16];
    __shared__ int   sPerm[24];
    __shared__ int   sSub[4];
    __shared__ int   sPos[16];
    const int t = threadIdx.x;
    const int b_s = blockIdx.x >> 3;
    const int node0 = (blockIdx.x & 7) * 16;
    const int g = b_s >> 4;
    if (t < 24) sPerm[t] = allperm[t];
    if (t < 4) sSub[t] = subgs[b_s * 4 + t];
    {
        int j = t >> 7, c = t & 127;
        sEm[j][c] = idemb[j * 128 + c] - 1.f;
        sEm[j + 2][c] = idemb[(j + 2) * 128 + c] - 1.f;
    }
    __syncthreads();
    if (t < 16) {
        sDg[t] = degf[g * 128 + node0 + t];
        int pos = -1;
        #pragma unroll
        for (int q = 0; q < 4; ++q) if (sSub[q] == node0 + t) pos = q;
        sPos[t] = pos;
    }
    if (t < 64) {
        int il = t >> 2, q = t & 3;
        sAq[il][q] = adj[((size_t)(g * 128 + node0 + il)) * 128 + sSub[q]];
    }
    __syncthreads();
    // stage 1: m rows (closed form), column-parallel
    {
        const int c = t & 127, rhalf = t >> 7;
        #pragma unroll
        for (int il8 = 0; il8 < 8; ++il8) {
            int il = rhalf * 8 + il8;
            float dg = sDg[il];
            float a0 = sAq[il][0], a1 = sAq[il][1], a2 = sAq[il][2], a3 = sAq[il][3];
            #pragma unroll
            for (int p = 0; p < 6; ++p) {
                float v = dg;
                v = fmaf(a0, sEm[sPerm[0*6 + p]][c], v);
                v = fmaf(a1, sEm[sPerm[1*6 + p]][c], v);
                v = fmaf(a2, sEm[sPerm[2*6 + p]][c], v);
                v = fmaf(a3, sEm[sPerm[3*6 + p]][c], v);
                int lr = il * 6 + p;
                smem[lr / 24][lr % 24][c] = f2s(v);
            }
        }
    }
    __syncthreads();
    // stage 2: MFMA MLP (24 valid rows per wave)
    const int lane = t & 63, wave = t >> 6;
    const int quad = lane >> 4, l16 = lane & 15;
    v4f acc[2][8];
    #pragma unroll
    for (int mt = 0; mt < 2; ++mt)
        #pragma unroll
        for (int nt = 0; nt < 8; ++nt) acc[mt][nt] = (v4f){0.f,0.f,0.f,0.f};
    #pragma unroll
    for (int kk = 0; kk < 4; ++kk) {
        v8s a0 = *(const v8s*)&smem[wave][l16][kk*32 + quad*8];
        v8s a1 = *(const v8s*)&smem[wave][16 + l16][kk*32 + quad*8];
        #pragma unroll
        for (int nt = 0; nt < 8; ++nt) {
            v8s b = *(const v8s*)(W1t + (nt*16 + l16)*128 + kk*32 + quad*8);
            acc[0][nt] = MFMA(a0, b, acc[0][nt]);
            acc[1][nt] = MFMA(a1, b, acc[1][nt]);
        }
    }
    #pragma unroll
    for (int nt = 0; nt < 8; ++nt) {
        float bb = b1[nt*16 + l16];
        #pragma unroll
        for (int mt = 0; mt < 2; ++mt)
            #pragma unroll
            for (int r = 0; r < 4; ++r)
                smem[wave][mt*16 + quad*4 + r][nt*16 + l16] = f2s(fmaxf(acc[mt][nt][r] + bb, 0.f));
    }
    #pragma unroll
    for (int mt = 0; mt < 2; ++mt)
        #pragma unroll
        for (int nt = 0; nt < 8; ++nt) acc[mt][nt] = (v4f){0.f,0.f,0.f,0.f};
    #pragma unroll
    for (int kk = 0; kk < 4; ++kk) {
        v8s a0 = *(const v8s*)&smem[wave][l16][kk*32 + quad*8];
        v8s a1 = *(const v8s*)&smem[wave][16 + l16][kk*32 + quad*8];
        #pragma unroll
        for (int nt = 0; nt < 8; ++nt) {
            v8s b = *(const v8s*)(W2t + (nt*16 + l16)*128 + kk*32 + quad*8);
            acc[0][nt] = MFMA(a0, b, acc[0][nt]);
            acc[1][nt] = MFMA(a1, b, acc[1][nt]);
        }
    }
    float bb2[8], gv[8], bv[8];
    #pragma unroll
    for (int nt = 0; nt < 8; ++nt) {
        int n = nt*16 + l16;
        bb2[nt] = b2[n]; gv[nt] = gam[n]; bv[nt] = bet[n];
    }
    #pragma unroll
    for (int mt = 0; mt < 2; ++mt)
        #pragma unroll
        for (int r = 0; r < 4; ++r) {
            float s = 0.f, q = 0.f;
            #pragma unroll
            for (int nt = 0; nt < 8; ++nt) {
                float u = acc[mt][nt][r] + bb2[nt];
                acc[mt][nt][r] = u; s += u; q += u*u;
            }
            #pragma unroll
            for (int d = 1; d < 16; d <<= 1) { s += __shfl_xor(s, d); q += __shfl_xor(q, d); }
            float mn = s * (1.f/128.f);
            float rs = rsqrtf(q * (1.f/128.f) - mn*mn + 1e-5f);
            int lrl = mt*16 + quad*4 + r;
            if (lrl < 24) {
                int lr = wave * 24 + lrl;
                int il = lr / 6, p = lr - il * 6;
                int pos = sPos[il];
                #pragma unroll
                for (int nt = 0; nt < 8; ++nt) {
                    int col = nt*16 + l16;
                    float self = (pos < 0) ? 1.f : (sEm[sPerm[pos*6 + p]][col] + 1.f);
                    float v = fmaxf((acc[mt][nt][r] - mn)*rs*gv[nt] + bv[nt], 0.f) + self;
                    smem[wave][lrl][col] = f2s(v);
                }
            }
        }
    __syncthreads();
    // stage 3: coalesced z2 store
    const size_t base = ((size_t)(b_s * 128 + node0)) * 6;
    #pragma unroll
    for (int k2 = 0; k2 < 6; ++k2) {
        int chunk = t + k2 * 256;               // 0..1535
        int row = chunk >> 4, c8 = chunk & 15;
        v8s v = *(const v8s*)&smem[row / 24][row % 24][c8 * 8];
        *(v8s*)(z2 + (base + row) * 128 + c8 * 8) = v;
    }
}

// ---------------- ID layer 2: one block per subgraph, LDS-staged spmv, p-loop,
// mean accumulated in registers; writes only zm ----------------
__global__ __launch_bounds__(256, 2) void k_id2(
    const bf16* __restrict__ z2, bf16* __restrict__ zm,
    const unsigned char* __restrict__ nbr, const int* __restrict__ deg,
    const int* __restrict__ num_node,
    const bf16* __restrict__ W1t, const float* __restrict__ b1,
    const bf16* __restrict__ W2t, const float* __restrict__ b2,
    const float* __restrict__ gam, const float* __restrict__ bet)
{
    __shared__ __align__(16) short sZ[128][136];
    __shared__ __align__(16) short sM[128][136];
    const int t = threadIdx.x, lane = t & 63, wave = t >> 6;
    const int quad = lane >> 4, l16 = lane & 15;
    const int b_s = blockIdx.x;
    const int g = b_s >> 4;
    const int nn = num_node[g];
    // per-thread gather assignment
    const int gi_i = t >> 1;                 // node 0..127 (each node handled by 2 threads)
    const int gcb = (t & 1) * 64;            // column base 0 or 64
    const int gcnt = deg[g * 128 + gi_i];
    const unsigned char* gnb = nbr + (size_t)(g * 128 + gi_i) * NBR_CAP;
    // per-lane epilogue params
    float bb1v[8], bb2[8], gv[8], bv[8];
    #pragma unroll
    for (int nt = 0; nt < 8; ++nt) {
        int n = nt*16 + l16;
        bb1v[nt] = b1[n]; bb2[nt] = b2[n]; gv[nt] = gam[n]; bv[nt] = bet[n];
    }
    float meanAcc[2][8][4];
    #pragma unroll
    for (int mt = 0; mt < 2; ++mt)
        #pragma unroll
        for (int nt = 0; nt < 8; ++nt)
            #pragma unroll
            for (int r = 0; r < 4; ++r) meanAcc[mt][nt][r] = 0.f;

    for (int p = 0; p < P_; ++p) {
        // ---- stage z2[b,:,p,:] into sZ (coalesced v8s) ----
        #pragma unroll
        for (int it = 0; it < 8; ++it) {
            int idx = it * 256 + t;
            int j = idx >> 4, c8 = idx & 15;
            *(v8s*)&sZ[j][c8 * 8] =
                *(const v8s*)(z2 + ((size_t)(b_s * 128 + j)) * 768 + p * 128 + c8 * 8);
        }
        __syncthreads();
        // ---- gather from LDS: m[i, cols] = sum_{j in N(i)} sZ[j][cols] ----
        #pragma unroll
        for (int qq = 0; qq < 2; ++qq) {
            int c0 = gcb + qq * 32;
            float a[32];
            #pragma unroll
            for (int u = 0; u < 32; ++u) a[u] = 0.f;
            for (int c = 0; c < gcnt; ++c) {
                const short* zr = &sZ[gnb[c]][c0];
                #pragma unroll
                for (int v = 0; v < 4; ++v) {
                    v8s z8 = *(const v8s*)(zr + v * 8);
                    #pragma unroll
                    for (int u = 0; u < 8; ++u) a[v * 8 + u] += s2f(z8[u]);
                }
            }
            #pragma unroll
            for (int v = 0; v < 4; ++v) {
                v8s o;
                #pragma unroll
                for (int u = 0; u < 8; ++u) o[u] = f2s(a[v * 8 + u]);
                *(v8s*)&sM[gi_i][c0 + v * 8] = o;
            }
        }
        __syncthreads();
        // ---- MFMA MLP on rows wave*32..+31 of sM ----
        v4f acc[2][8];
        #pragma unroll
        for (int mt = 0; mt < 2; ++mt)
            #pragma unroll
            for (int nt = 0; nt < 8; ++nt) acc[mt][nt] = (v4f){0.f,0.f,0.f,0.f};
        #pragma unroll
        for (int kk = 0; kk < 4; ++kk) {
            v8s a0 = *(const v8s*)&sM[wave*32 + l16][kk*32 + quad*8];
            v8s a1 = *(const v8s*)&sM[wave*32 + 16 + l16][kk*32 + quad*8];
            #pragma unroll
            for (int nt = 0; nt < 8; ++nt) {
                v8s b = *(const v8s*)(W1t + (nt*16 + l16)*128 + kk*32 + quad*8);
                acc[0][nt] = MFMA(a0, b, acc[0][nt]);
                acc[1][nt] = MFMA(a1, b, acc[1][nt]);
            }
        }
        #pragma unroll
        for (int nt = 0; nt < 8; ++nt) {
            #pragma unroll
            for (int mt = 0; mt < 2; ++mt)
                #pragma unroll
                for (int r = 0; r < 4; ++r)
                    sM[wave*32 + mt*16 + quad*4 + r][nt*16 + l16] =
                        f2s(fmaxf(acc[mt][nt][r] + bb1v[nt], 0.f));
        }
        #pragma unroll
        for (int mt = 0; mt < 2; ++mt)
            #pragma unroll
            for (int nt = 0; nt < 8; ++nt) acc[mt][nt] = (v4f){0.f,0.f,0.f,0.f};
        #pragma unroll
        for (int kk = 0; kk < 4; ++kk) {
            v8s a0 = *(const v8s*)&sM[wave*32 + l16][kk*32 + quad*8];
            v8s a1 = *(const v8s*)&sM[wave*32 + 16 + l16][kk*32 + quad*8];
            #pragma unroll
            for (int nt = 0; nt < 8; ++nt) {
                v8s b = *(const v8s*)(W2t + (nt*16 + l16)*128 + kk*32 + quad*8);
                acc[0][nt] = MFMA(a0, b, acc[0][nt]);
                acc[1][nt] = MFMA(a1, b, acc[1][nt]);
            }
        }
        // ---- LN + relu + residual(sZ) -> accumulate p-mean in registers ----
        #pragma unroll
        for (int mt = 0; mt < 2; ++mt)
            #pragma unroll
            for (int r = 0; r < 4; ++r) {
                float s = 0.f, q = 0.f;
                #pragma unroll
                for (int nt = 0; nt < 8; ++nt) {
                    float u = acc[mt][nt][r] + bb2[nt];
                    acc[mt][nt][r] = u; s += u; q += u*u;
                }
                #pragma unroll
                for (int d = 1; d < 16; d <<= 1) { s += __shfl_xor(s, d); q += __shfl_xor(q, d); }
                float mn = s * (1.f/128.f);
                float rs = rsqrtf(q * (1.f/128.f) - mn*mn + 1e-5f);
                int row = wave*32 + mt*16 + quad*4 + r;
                #pragma unroll
                for (int nt = 0; nt < 8; ++nt) {
                    int col = nt*16 + l16;
                    float v = fmaxf((acc[mt][nt][r] - mn)*rs*gv[nt] + bv[nt], 0.f);
                    v += s2f(sZ[row][col]);
                    meanAcc[mt][nt][r] += v;
                }
            }
        __syncthreads();   // sZ/sM reused next p
    }
    // ---- write zm: mean/6, masked, route through sM for coalesced stores ----
    #pragma unroll
    for (int mt = 0; mt < 2; ++mt)
        #pragma unroll
        for (int r = 0; r < 4; ++r) {
            int row = wave*32 + mt*16 + quad*4 + r;
            bool nul = (row >= nn);
            #pragma unroll
            for (int nt = 0; nt < 8; ++nt)
                sM[row][nt*16 + l16] = f2s(nul ? 0.f : meanAcc[mt][nt][r] * (1.f/6.f));
        }
    __syncthreads();
    #pragma unroll
    for (int it = 0; it < 8; ++it) {
        int idx = it * 256 + t;
        int row = idx >> 4, c8 = idx & 15;
        *(v8s*)(zm + ((size_t)(b_s * 128 + row)) * 128 + c8 * 8) = *(const v8s*)&sM[row][c8 * 8];
    }
}

// ---------------- gl layer: gather + MFMA MLP + LN + residual (ping-pong) ----------------
__global__ __launch_bounds__(256) void k_gl_fused(
    const float* __restrict__ hsA, float* __restrict__ hsB,
    const unsigned char* __restrict__ nbr, const int* __restrict__ deg,
    const bf16* __restrict__ W1t, const float* __restrict__ b1,
    const bf16* __restrict__ W2t, const float* __restrict__ b2,
    const float* __restrict__ gam, const float* __restrict__ bet)
{
    __shared__ __align__(16) short smem[4][16][136];
    const int t = threadIdx.x, lane = t & 63, wave = t >> 6;
    const int quad = lane >> 4, l16 = lane & 15;
    const int b_s = blockIdx.x >> 1;
    const int node0 = (blockIdx.x & 1) * 64;
    const int g = b_s >> 4;
    const float* hblk = hsA + (size_t)b_s * 128 * 128;
    {
        const float* hp = hblk + lane * 2;
        for (int r = 0; r < 16; ++r) {
            int gi = g * 128 + node0 + wave * 16 + r;
            int cnt = deg[gi];
            const unsigned char* nb = nbr + (size_t)gi * NBR_CAP;
            float a0 = 0.f, a1 = 0.f;
            for (int c = 0; c < cnt; ++c) {
                const float* qp = hp + (int)nb[c] * 128;
                a0 += qp[0]; a1 += qp[1];
            }
            *(unsigned*)&smem[wave][r][lane * 2] = pack2(a0, a1);
        }
    }
    v4f acc[8];
    #pragma unroll
    for (int nt = 0; nt < 8; ++nt) acc[nt] = (v4f){0.f,0.f,0.f,0.f};
    #pragma unroll
    for (int kk = 0; kk < 4; ++kk) {
        v8s a = *(const v8s*)&smem[wave][l16][kk*32 + quad*8];
        #pragma unroll
        for (int nt = 0; nt < 8; ++nt) {
            v8s b = *(const v8s*)(W1t + (nt*16 + l16)*128 + kk*32 + quad*8);
            acc[nt] = MFMA(a, b, acc[nt]);
        }
    }
    #pragma unroll
    for (int nt = 0; nt < 8; ++nt) {
        float bb = b1[nt*16 + l16];
        #pragma unroll
        for (int r = 0; r < 4; ++r)
            smem[wave][quad*4 + r][nt*16 + l16] = f2s(fmaxf(acc[nt][r] + bb, 0.f));
    }
    #pragma unroll
    for (int nt = 0; nt < 8; ++nt) acc[nt] = (v4f){0.f,0.f,0.f,0.f};
    #pragma unroll
    for (int kk = 0; kk < 4; ++kk) {
        v8s a = *(const v8s*)&smem[wave][l16][kk*32 + quad*8];
        #pragma unroll
        for (int nt = 0; nt < 8; ++nt) {
            v8s b = *(const v8s*)(W2t + (nt*16 + l16)*128 + kk*32 + quad*8);
            acc[nt] = MFMA(a, b, acc[nt]);
        }
    }
    float bb2[8], gv[8], bv[8];
    #pragma unroll
    for (int nt = 0; nt < 8; ++nt) {
        int n = nt*16 + l16;
        bb2[nt] = b2[n]; gv[nt] = gam[n]; bv[nt] = bet[n];
    }
    #pragma unroll
    for (int r = 0; r < 4; ++r) {
        float s = 0.f, q = 0.f;
        #pragma unroll
        for (int nt = 0; nt < 8; ++nt) {
            float u = acc[nt][r] + bb2[nt];
            acc[nt][r] = u; s += u; q += u*u;
        }
        #pragma unroll
        for (int d = 1; d < 16; d <<= 1) { s += __shfl_xor(s, d); q += __shfl_xor(q, d); }
        float mn = s * (1.f/128.f);
        float rs = rsqrtf(q * (1.f/128.f) - mn*mn + 1e-5f);
        size_t gr = ((size_t)b_s * 128 + node0 + wave*16 + quad*4 + r) * 128;
        #pragma unroll
        for (int nt = 0; nt < 8; ++nt) {
            int col = nt*16 + l16;
            float v = fmaxf((acc[nt][r] - mn)*rs*gv[nt] + bv[nt], 0.f);
            hsB[gr + col] = v + hsA[gr + col];
        }
    }
}

// ---------------- hs.sum(axis=1) ----------------
__global__ __launch_bounds__(128) void k_hssum(const float* __restrict__ hs, float* __restrict__ hsum)
{
    const int b_s = blockIdx.x, hd = threadIdx.x;
    float v = 0.f;
    const float* r = hs + (size_t)b_s * 128 * H_ + hd;
    for (int i = 0; i < 128; ++i) v += r[(size_t)i * H_];
    hsum[(size_t)b_s * H_ + hd] = v;
}

// ---------------- segment max over 16 subgraphs per graph ----------------
__global__ __launch_bounds__(128) void k_maxpool(const float* __restrict__ hs2, float* __restrict__ pooled)
{
    const int g = blockIdx.x, hd = threadIdx.x;
    float m = -INFINITY;
    for (int s = 0; s < 16; ++s) m = fmaxf(m, hs2[((size_t)(g * 16 + s)) * H_ + hd]);
    pooled[(size_t)g * H_ + hd] = m;
}

// ---------------- final projection ----------------
__global__ __launch_bounds__(128) void k_out(const float* __restrict__ pooled2,
    const float* __restrict__ out_W, const float* __restrict__ out_b, float* __restrict__ out)
{
    __shared__ float red[128];
    const int g = blockIdx.x, hd = threadIdx.x;
    red[hd] = pooled2[(size_t)g * H_ + hd] * out_W[hd];
    __syncthreads();
    for (int s = 64; s > 0; s >>= 1) {
        if (hd < s) red[hd] += red[hd + s];
        __syncthreads();
    }
    if (hd == 0) out[g] = red[0] + out_b[0];
}

extern "C" void kernel_launch(void* const* d_in, const int* in_sizes, int n_in,
                              void* d_out, int out_size, void* d_ws, size_t ws_size,
                              hipStream_t stream)
{
    (void)in_sizes; (void)n_in; (void)out_size; (void)ws_size;
    const float* x     = (const float*)d_in[0];
    const float* adj   = (const float*)d_in[1];
    const float* idemb = (const float*)d_in[2];
    const float* in_W1 = (const float*)d_in[3];
    const float* in_b1 = (const float*)d_in[4];
    const float* in_W2 = (const float*)d_in[5];
    const float* in_b2 = (const float*)d_in[6];
    const float* in_g  = (const float*)d_in[7];
    const float* in_bn = (const float*)d_in[8];
    const float* gW1   = (const float*)d_in[9];
    const float* gb1   = (const float*)d_in[10];
    const float* gW2   = (const float*)d_in[11];
    const float* gb2   = (const float*)d_in[12];
    const float* gg    = (const float*)d_in[13];
    const float* gbn   = (const float*)d_in[14];
    const float* iW1   = (const float*)d_in[15];
    const float* ib1   = (const float*)d_in[16];
    const float* iW2   = (const float*)d_in[17];
    const float* ib2   = (const float*)d_in[18];
    const float* ig    = (const float*)d_in[19];
    const float* ibn   = (const float*)d_in[20];
    const float* glW1  = (const float*)d_in[21];
    const float* glb1  = (const float*)d_in[22];
    const float* glW2  = (const float*)d_in[23];
    const float* glb2  = (const float*)d_in[24];
    const float* glg   = (const float*)d_in[25];
    const float* glbn  = (const float*)d_in[26];
    const float* s1_W  = (const float*)d_in[27];
    const float* s1_b  = (const float*)d_in[28];
    const float* s2_W  = (const float*)d_in[29];
    const float* s2_b  = (const float*)d_in[30];
    const float* rW1   = (const float*)d_in[31];
    const float* rb1   = (const float*)d_in[32];
    const float* rW2   = (const float*)d_in[33];
    const float* rb2   = (const float*)d_in[34];
    const float* rg    = (const float*)d_in[35];
    const float* rbn   = (const float*)d_in[36];
    const float* out_W = (const float*)d_in[37];
    const float* out_b = (const float*)d_in[38];
    const int* subgs   = (const int*)d_in[39];
    const int* num_node= (const int*)d_in[41];
    const int* allperm = (const int*)d_in[42];

    // ---- workspace layout (peak ~123 MB; same budget as passing R3) ----
    const size_t MB_ = (size_t)512 * 128 * P_ * H_ * 2;        // 100,663,296: z2
    char* w = (char*)d_ws;
    bf16*  z2b    = (bf16*)(w);                                 // region A: z2
    float* hsA    = (float*)(w);                                // region A reuse (z2 dead)
    float* hsB    = (float*)(w + 33554432ull);                  // region A reuse
    bf16*  zm     = (bf16*)(w + MB_);                           // (512,128,128) bf16 = 16.8 MB
    bf16*  WT     = (bf16*)(w + MB_ + 16777216ull);             // 15 x (128x128) bf16 transposed
    char*  wc     = w + MB_ + 16777216ull + 524288ull;
    float* hb     = (float*)(wc);                               // h (32,128,128) f32  2 MB
    float* sb2    = (float*)(wc + 2097152ull);                  // t1 / g-layer msgs    2 MB
    float* hsum   = (float*)(wc + 4194304ull);                  // (512,128)
    float* hs2    = (float*)(wc + 4456448ull);                  // (512,128)
    float* pooled = (float*)(wc + 4718592ull);                  // (32,128)
    float* pooled2= (float*)(wc + 4734976ull);                  // (32,128)
    unsigned char* nbr = (unsigned char*)(wc + 4751360ull);     // 4096*48 u8
    int*   deg    = (int*)(wc + 4947968ull);                    // 4096 i32
    float* degf   = (float*)(wc + 4964352ull);                  // 4096 f32
    float* outp   = (float*)d_out;

    // prep: CSR + transposed bf16 weights
    k_csr<<<32, 128, 0, stream>>>(adj, nbr, deg, degf);
    k_wt<<<1920, 128, 0, stream>>>(in_W2, gW1, gW2, iW1, iW2, glW1, glW2, WT);

    // input embedding block: h = block(x)  (known-good VALU path)
    k_in_t1<<<4096, 128, 0, stream>>>(x, in_W1, in_b1, sb2);
    k_block<false, false><<<256, 128, 0, stream>>>(sb2, nullptr, hb,
        nullptr, nullptr, in_W2, in_b2, in_g, in_bn);

    // graph message passing (3 layers) on h
    for (int l = 0; l < 3; ++l) {
        k_spmv<<<4096, 128, 0, stream>>>(adj, hb, sb2, 0);
        k_block<true, true><<<256, 128, 0, stream>>>(sb2, hb, hb,
            gW1 + l * 16384, gb1 + l * 128, gW2 + l * 16384, gb2 + l * 128,
            gg + l * 128, gbn + l * 128);
    }

    // ID layer 1 fully fused -> z2
    k_id1_fused<<<4096, 256, 0, stream>>>(adj, degf, subgs, allperm, idemb, z2b,
        WT + (size_t)7 * 16384, ib1, WT + (size_t)8 * 16384, ib2, ig, ibn);

    // ID layer 2: block-per-subgraph, LDS-staged -> zm
    k_id2<<<512, 256, 0, stream>>>(z2b, zm, nbr, deg, num_node,
        WT + (size_t)9 * 16384, ib1 + 128, WT + (size_t)10 * 16384, ib2 + 128, ig + 128, ibn + 128);

    // setmlp1 with gathered residual h[subgbatch] -> hsA (region A; z2 now dead)
    k_gemm_relu<true, bf16><<<4096, 128, 0, stream>>>(zm, hb, hsA, s1_W, s1_b);

    // global message passing on subgraph copies (2 layers), ping-pong hsA/hsB
    k_gl_fused<<<1024, 256, 0, stream>>>(hsA, hsB, nbr, deg,
        WT + (size_t)11 * 16384, glb1, WT + (size_t)12 * 16384, glb2, glg, glbn);
    k_gl_fused<<<1024, 256, 0, stream>>>(hsB, hsA, nbr, deg,
        WT + (size_t)13 * 16384, glb1 + 128, WT + (size_t)14 * 16384, glb2 + 128, glg + 128, glbn + 128);

    // node sum -> setmlp2 -> segment max -> setmlp3 block -> output proj
    k_hssum<<<512, 128, 0, stream>>>(hsA, hsum);
    k_gemm_relu<false, float><<<32, 128, 0, stream>>>(hsum, nullptr, hs2, s2_W, s2_b);
    k_maxpool<<<32, 128, 0, stream>>>(hs2, pooled);
    k_block<true, true><<<2, 128, 0, stream>>>(pooled, pooled, pooled2,
        rW1, rb1, rW2, rb2, rg, rbn);
    k_out<<<32, 128, 0, stream>>>(pooled2, out_W, out_b, outp);
}